// Round 4
// baseline (197.404 us; speedup 1.0000x reference)
//
#include <hip/hip_runtime.h>

// HolonomyAttention: out = softmax_causal((Q @ C_h) K^T / sqrt(D)) V
// B=2 H=16 T=2048 D=64, fp32 in/out.
// Round 4: barrier-free attention (direct global b128 fragment loads, DPP
// softmax reductions, exp2 domain) + vectorized prepass (qrot in A-frag order,
// K bf16 natural, V^T bf16).

typedef __attribute__((ext_vector_type(8))) short short8;           // 8 bf16
typedef __attribute__((ext_vector_type(8))) unsigned short ushort8;
typedef __attribute__((ext_vector_type(4))) float f32x4;

constexpr int Tc = 2048;
constexpr int Dc = 64;
constexpr size_t HEAD_ELEMS = (size_t)Tc * Dc;       // 131072
constexpr size_t REGION = (size_t)32 * HEAD_ELEMS;   // 4,194,304 u16 = 8 MiB

__device__ inline unsigned short f2bf(float f) {   // fp32 -> bf16 RNE
    union { float f; unsigned u; } x; x.f = f;
    return (unsigned short)((x.u + 0x7fffu + ((x.u >> 16) & 1u)) >> 16);
}

// DPP lane-shuffle within 16-lane rows (pure VALU, no LDS)
template<int CTRL>
__device__ inline float dppf(float x) {
    int r = __builtin_amdgcn_update_dpp(0, __builtin_bit_cast(int, x), CTRL, 0xF, 0xF, true);
    return __builtin_bit_cast(float, r);
}
__device__ inline float rowmax16(float v) {
    v = fmaxf(v, dppf<0xB1>(v));    // quad_perm [1,0,3,2]  : xor 1
    v = fmaxf(v, dppf<0x4E>(v));    // quad_perm [2,3,0,1]  : xor 2
    v = fmaxf(v, dppf<0x141>(v));   // row_half_mirror      : other quad of 8
    v = fmaxf(v, dppf<0x140>(v));   // row_mirror           : other half of 16
    return v;
}
__device__ inline float rowsum16(float v) {
    v += dppf<0xB1>(v);
    v += dppf<0x4E>(v);
    v += dppf<0x141>(v);
    v += dppf<0x140>(v);
    return v;
}

#define MFMA16(a, b, c) __builtin_amdgcn_mfma_f32_16x16x32_bf16((a), (b), (c), 0, 0, 0)

// ---------------------------------------------------------------------------
// Pre-pass, one block per (bh, 64-row tile):
//   qfrag_g : Qrot * (0.125*log2e), bf16, stored in A-FRAGMENT order
//             [strip16][kh][lane] (16 B/lane, coalesced both sides)
//   kb_g    : K bf16, natural [s][d]
//   vT_g    : V^T bf16, [d][s] per head
// ---------------------------------------------------------------------------
__global__ __launch_bounds__(256, 2)
void holo_prep(const float* __restrict__ Qp, const float* __restrict__ Kp,
               const float* __restrict__ Vp, const float* __restrict__ Cp,
               unsigned short* __restrict__ qfrag_g,
               unsigned short* __restrict__ kb_g,
               unsigned short* __restrict__ vT_g)
{
    __shared__ unsigned short qt[64 * 72];   // Q tile bf16 natural
    __shared__ float vs32[64 * 68];          // V tile fp32 natural
    __shared__ float c32[64 * 68];           // C tile fp32 natural
    __shared__ unsigned short pf[64 * 72];   // Qrot C->A round trip

    const int t = threadIdx.x, lane = t & 63, wid = t >> 6;
    const int l15 = lane & 15, quad = lane >> 4, wb = wid * 16;
    const int n = blockIdx.x, bh = n >> 5, st = n & 31, h = bh & 15;
    const int s0 = st * 64;

    const float* Qg = Qp + ((size_t)bh * Tc + s0) * Dc;
    const float* Kg = Kp + ((size_t)bh * Tc + s0) * Dc;
    const float* Vg = Vp + ((size_t)bh * Tc + s0) * Dc;
    const float* Cg = Cp + (size_t)h * Dc * Dc;

    #pragma unroll
    for (int kk = 0; kk < 4; ++kk) {
        const int flat = kk * 1024 + t * 4;   // coalesced float4
        const int r = flat >> 6, d0 = flat & 63;
        float4 qv = *(const float4*)(&Qg[flat]);
        ushort4 qp; qp.x = f2bf(qv.x); qp.y = f2bf(qv.y); qp.z = f2bf(qv.z); qp.w = f2bf(qv.w);
        *(ushort4*)(&qt[r * 72 + d0]) = qp;
        float4 kv = *(const float4*)(&Kg[flat]);
        ushort4 kp; kp.x = f2bf(kv.x); kp.y = f2bf(kv.y); kp.z = f2bf(kv.z); kp.w = f2bf(kv.w);
        *(ushort4*)(&kb_g[(size_t)bh * HEAD_ELEMS + (size_t)(s0 + r) * 64 + d0]) = kp;
        *(float4*)(&vs32[r * 68 + d0]) = *(const float4*)(&Vg[flat]);
        *(float4*)(&c32[r * 68 + d0]) = *(const float4*)(&Cg[flat]);
    }
    __syncthreads();

    // ---- Qrot strip (rows wb..wb+15) via MFMA; B-frag gathered from c32 ----
    {
        short8 a0 = *(const short8*)(&qt[(wb + l15) * 72 + quad * 8]);
        short8 a1 = *(const short8*)(&qt[(wb + l15) * 72 + 32 + quad * 8]);
        #pragma unroll
        for (int tn = 0; tn < 4; ++tn) {
            short8 b0, b1;   // B[n=e][k=d] = C[d][e]
            #pragma unroll
            for (int jj = 0; jj < 8; ++jj) {
                b0[jj] = (short)f2bf(c32[(quad * 8 + jj) * 68 + tn * 16 + l15]);
                b1[jj] = (short)f2bf(c32[(32 + quad * 8 + jj) * 68 + tn * 16 + l15]);
            }
            f32x4 c = {0.f, 0.f, 0.f, 0.f};
            c = MFMA16(a0, b0, c);
            c = MFMA16(a1, b1, c);
            #pragma unroll
            for (int i = 0; i < 4; ++i)   // fold scale * log2(e) = 0.125*1.4426950
                pf[(wb + quad * 4 + i) * 72 + tn * 16 + l15] = f2bf(c[i] * 0.18033688f);
        }
        __threadfence_block();   // wave-local pf: order writes before frag reads
        short8 fa0 = *(const short8*)(&pf[(wb + l15) * 72 + quad * 8]);
        short8 fa1 = *(const short8*)(&pf[(wb + l15) * 72 + 32 + quad * 8]);
        const size_t strip = (size_t)bh * 128 + st * 4 + wid;
        *(short8*)(&qfrag_g[strip * 1024 + lane * 8]) = fa0;
        *(short8*)(&qfrag_g[strip * 1024 + 512 + lane * 8]) = fa1;
    }

    // ---- V^T: thread owns col d = t>>2, rows g4*16..+16 ----
    {
        const int d = t >> 2, g4 = t & 3;
        ushort8 v0, v1;
        #pragma unroll
        for (int i = 0; i < 8; ++i) v0[i] = f2bf(vs32[(g4 * 16 + i) * 68 + d]);
        #pragma unroll
        for (int i = 0; i < 8; ++i) v1[i] = f2bf(vs32[(g4 * 16 + 8 + i) * 68 + d]);
        unsigned short* dst = vT_g + (size_t)bh * HEAD_ELEMS + (size_t)d * Tc + s0 + g4 * 16;
        *(ushort8*)(dst) = v0;
        *(ushort8*)(dst + 8) = v1;
    }
}

// ---------------------------------------------------------------------------
// Attention: barrier-free. BQ=128 (2 strips/wave), BK=64. K/V fragments
// loaded directly from global (coalesced b128, L2-resident per XCD).
// ---------------------------------------------------------------------------
__global__ __launch_bounds__(256, 2)
void holo_attn4(const unsigned short* __restrict__ qfrag_g,
                const unsigned short* __restrict__ kb_g,
                const unsigned short* __restrict__ vT_g,
                float* __restrict__ Op)
{
    __shared__ unsigned short pt[128 * 72];   // P round-trip, wave-local rows

    const int t = threadIdx.x, lane = t & 63, wid = t >> 6;
    const int l15 = lane & 15, quad = lane >> 4, wb = wid * 16;

    // XCD-grouped, work-balanced mapping: XCD x owns bh in [4x, 4x+4)
    const int id = blockIdx.x;
    const int xcd = id & 7, slot = id >> 3;
    const int bh = xcd * 4 + (slot & 3);
    const int u = slot >> 2;                  // 0..15
    const int qi = (u < 8) ? u : 23 - u;      // pairs (u, 15-u) -> 36 tiles/CU
    const int q0 = qi * 128;
    const int jmax = 2 * qi + 1;

    // Q_rot A-fragments (coalesced b128 global loads)
    short8 qa[2][2];
    #pragma unroll
    for (int s2 = 0; s2 < 2; ++s2) {
        const size_t strip = (size_t)bh * 128 + qi * 8 + s2 * 4 + wid;
        qa[s2][0] = *(const short8*)(&qfrag_g[strip * 1024 + lane * 8]);
        qa[s2][1] = *(const short8*)(&qfrag_g[strip * 1024 + 512 + lane * 8]);
    }

    const unsigned short* kb = kb_g + (size_t)bh * HEAD_ELEMS;
    const unsigned short* vb = vT_g + (size_t)bh * HEAD_ELEMS;

    float m_run[2][4], l_run[2][4];
    f32x4 o[2][4];
    #pragma unroll
    for (int s2 = 0; s2 < 2; ++s2)
        #pragma unroll
        for (int i = 0; i < 4; ++i) {
            m_run[s2][i] = -1e30f; l_run[s2][i] = 0.f;
            o[s2][i] = f32x4{0.f, 0.f, 0.f, 0.f};
        }

    for (int j = 0; j <= jmax; ++j) {
        const bool act0 = (j < jmax);   // strip0 fully masked at j==jmax

        // ---- K and V^T fragments: coalesced b128 global loads, issued early ----
        short8 kf[4][2], vf[4][2];
        #pragma unroll
        for (int tn = 0; tn < 4; ++tn) {
            const unsigned short* kr = kb + (size_t)(j * 64 + tn * 16 + l15) * 64 + quad * 8;
            kf[tn][0] = *(const short8*)(kr);
            kf[tn][1] = *(const short8*)(kr + 32);
            const unsigned short* vr = vb + (size_t)(tn * 16 + l15) * Tc + j * 64 + quad * 8;
            vf[tn][0] = *(const short8*)(vr);
            vf[tn][1] = *(const short8*)(vr + 32);
        }

        // ---- S = Qrot K^T (already in log2 domain: scale folded into qrot) ----
        f32x4 s[2][4];
        #pragma unroll
        for (int tn = 0; tn < 4; ++tn) {
            if (act0) {
                f32x4 c = {0.f, 0.f, 0.f, 0.f};
                c = MFMA16(qa[0][0], kf[tn][0], c);
                c = MFMA16(qa[0][1], kf[tn][1], c);
                s[0][tn] = c;
            }
            f32x4 c1 = {0.f, 0.f, 0.f, 0.f};
            c1 = MFMA16(qa[1][0], kf[tn][0], c1);
            c1 = MFMA16(qa[1][1], kf[tn][1], c1);
            s[1][tn] = c1;
        }

        // ---- mask + online softmax (DPP reductions, exp2 domain) ----
        #pragma unroll
        for (int s2 = 0; s2 < 2; ++s2) {
            if (s2 == 0 && !act0) continue;
            if (j >= 2 * qi + s2) {   // diagonal tile for this strip
                #pragma unroll
                for (int tn = 0; tn < 4; ++tn)
                    #pragma unroll
                    for (int i = 0; i < 4; ++i) {
                        const int rowg = q0 + s2 * 64 + wb + quad * 4 + i;
                        const int colg = j * 64 + tn * 16 + l15;
                        if (colg > rowg) s[s2][tn][i] = -1e30f;
                    }
            }
            #pragma unroll
            for (int i = 0; i < 4; ++i) {
                float v = fmaxf(fmaxf(s[s2][0][i], s[s2][1][i]),
                                fmaxf(s[s2][2][i], s[s2][3][i]));
                v = rowmax16(v);
                const float mn = fmaxf(m_run[s2][i], v);
                const float alpha = __builtin_amdgcn_exp2f(m_run[s2][i] - mn);
                m_run[s2][i] = mn;
                float acc = 0.f;
                #pragma unroll
                for (int tn = 0; tn < 4; ++tn) {
                    const float p = __builtin_amdgcn_exp2f(s[s2][tn][i] - mn);
                    s[s2][tn][i] = p;
                    acc += p;
                }
                acc = rowsum16(acc);
                l_run[s2][i] = l_run[s2][i] * alpha + acc;
                o[s2][0][i] *= alpha; o[s2][1][i] *= alpha;
                o[s2][2][i] *= alpha; o[s2][3][i] *= alpha;
            }
            #pragma unroll
            for (int tn = 0; tn < 4; ++tn)
                #pragma unroll
                for (int i = 0; i < 4; ++i)
                    pt[(s2 * 64 + wb + quad * 4 + i) * 72 + tn * 16 + l15] = f2bf(s[s2][tn][i]);
        }
        __threadfence_block();   // wave-local pt: order writes before A-frag reads

        // ---- O += P V ----
        short8 pa[2][2];
        #pragma unroll
        for (int s2 = 0; s2 < 2; ++s2) {
            if (s2 == 0 && !act0) continue;
            pa[s2][0] = *(const short8*)(&pt[(s2 * 64 + wb + l15) * 72 + quad * 8]);
            pa[s2][1] = *(const short8*)(&pt[(s2 * 64 + wb + l15) * 72 + 32 + quad * 8]);
        }
        #pragma unroll
        for (int tn = 0; tn < 4; ++tn) {
            if (act0) {
                o[0][tn] = MFMA16(pa[0][0], vf[tn][0], o[0][tn]);
                o[0][tn] = MFMA16(pa[0][1], vf[tn][1], o[0][tn]);
            }
            o[1][tn] = MFMA16(pa[1][0], vf[tn][0], o[1][tn]);
            o[1][tn] = MFMA16(pa[1][1], vf[tn][1], o[1][tn]);
        }
    }

    // ---- epilogue ----
    #pragma unroll
    for (int s2 = 0; s2 < 2; ++s2)
        #pragma unroll
        for (int i = 0; i < 4; ++i) {
            const float inv = 1.0f / l_run[s2][i];
            const int rowg = q0 + s2 * 64 + wb + quad * 4 + i;
            float* dst = Op + ((size_t)bh * Tc + rowg) * Dc;
            #pragma unroll
            for (int tn = 0; tn < 4; ++tn)
                dst[tn * 16 + l15] = o[s2][tn][i] * inv;
        }
}

extern "C" void kernel_launch(void* const* d_in, const int* in_sizes, int n_in,
                              void* d_out, int out_size, void* d_ws, size_t ws_size,
                              hipStream_t stream) {
    const float* Q = (const float*)d_in[0];
    const float* K = (const float*)d_in[1];
    const float* V = (const float*)d_in[2];
    // d_in[3] = causal mask (analytic — unused)
    const float* C = (const float*)d_in[4];
    float* O = (float*)d_out;

    unsigned short* qfrag_w = (unsigned short*)d_ws;   // 8 MiB
    unsigned short* kb_w    = qfrag_w + REGION;        // 8 MiB
    unsigned short* vT_w    = kb_w + REGION;           // 8 MiB (24 MiB total)

    holo_prep<<<dim3(1024), dim3(256), 0, stream>>>(Q, K, V, C, qfrag_w, kb_w, vT_w);
    holo_attn4<<<dim3(512), dim3(256), 0, stream>>>(qfrag_w, kb_w, vT_w, O);
}